// Round 6
// baseline (402.620 us; speedup 1.0000x reference)
//
#include <hip/hip_runtime.h>
#include <stdint.h>

typedef unsigned long long u64;
typedef short v8s __attribute__((ext_vector_type(8)));   // 8 bf16 (4 VGPRs) — MFMA A/B frag
typedef float v4f __attribute__((ext_vector_type(4)));   // MFMA C/D frag

__device__ __forceinline__ unsigned short f2bf_rne(float f) {
  union { float f; unsigned u; } c; c.f = f;
  unsigned u = c.u;
  u += 0x7fffu + ((u >> 16) & 1u);   // round-to-nearest-even
  return (unsigned short)(u >> 16);
}

// unpack bf16x8 pair (z,a), accumulate S[k] += z[k] - a[k]
__device__ __forceinline__ void bacc(uint4 z, uint4 a, float* S) {
  const unsigned* zp = &z.x;
  const unsigned* ap = &a.x;
  #pragma unroll
  for (int k = 0; k < 4; k++) {
    unsigned zu = zp[k], au = ap[k];
    S[2 * k]     += __uint_as_float(zu << 16)         - __uint_as_float(au << 16);
    S[2 * k + 1] += __uint_as_float(zu & 0xffff0000u) - __uint_as_float(au & 0xffff0000u);
  }
}

// ============================================================================
// FAST PATH (ws >= 127 KB): prepack2 + ONE fully-fused kernel.
//
// Register-cliff ledger (rounds 1-5):
//   At launch_bounds(512,4) (=128 regs/wave) the tap loop + 48 acc AGPRs has
//   ZERO spare regs; any extra live value spills (~+70MB FETCH/WRITE, +18us).
//   Round 5 fused with acc LIVE ACROSS the conv1 sweep at (512,4): WRITE
//   282MB, 271us — catastrophic spill, as the tripwire predicted.
// THIS round's fix: (a) reorder so acc is never live across the sweep
//   (sweep both halves -> LDS first, then all taps), and (b) full-Xs LDS
//   (139776 B) forces 1 block/CU anyway, so launch_bounds(512,2) = 256
//   regs/wave — the 128-reg cliff no longer exists in this kernel.
// Spill tripwire: WRITE_SIZE > 10 MB (only `out` ~2MB is legitimate).
// ============================================================================

// prepack2: weight-only packing, one thread per element, 124*512 = 63488.
//  idx < 51200 : Wr[h*25600 + c*800 + tap*32 + chh] = w2[c][h*32+chh][tap]
//  else        : Gt original full layout G[ch][cls16][j6][cout64]:
//    value = sum_{i=ia..ib} sum_{jj<j} w1[cout][ch][i][jj]
__global__ __launch_bounds__(512) void prepack2(
    const float* __restrict__ w1,       // [64][2][5][5]
    const float* __restrict__ w2,       // [32][64][5][5]
    unsigned short* __restrict__ Wr,    // [2][32][800] bf16
    unsigned short* __restrict__ Gt)    // [2][16][6][64] bf16 = 12288
{
  int idx = blockIdx.x * 512 + threadIdx.x;
  if (idx < 51200) {
    int c = idx / 1600, rem = idx - c * 1600;
    int h = rem / 800, r2 = rem - h * 800;
    int tap = r2 >> 5, chh = r2 & 31;
    Wr[h * 25600 + c * 800 + r2] =
        f2bf_rne(w2[(c * 64 + h * 32 + chh) * 25 + tap]);
  } else {
    int e = idx - 51200;                // < 12288
    int ch = e / 6144, r = e - ch * 6144;
    int cls = r / 384, r2 = r - cls * 384;
    int j = r2 / 64, cout = r2 - j * 64;
    float v = 0.f;
    if (cls > 0) {
      int ia = 0, ib = 0;
      #pragma unroll
      for (int bb = 0; bb < 5; bb++) {
        int base = (bb * (bb + 1)) / 2 + 1;
        if (cls >= base && cls <= base + bb) { ib = bb; ia = cls - base; }
      }
      for (int i = ia; i <= ib; i++)
        for (int jj = 0; jj < j; jj++)
          v += w1[(cout * 2 + ch) * 25 + i * 5 + jj];
    }
    Gt[e] = f2bf_rne(v);
  }
}

// Fully-fused kernel, one block per image, 1 block/CU (LDS 139776 B):
//   LDS map: Xs[2][900][32] bf16 @0 (115200, slot-rotated — byte-identical
//   layout to the old staged XsG); G-LUT @115200 (24576).
//   Epilogue aliases: Cout (43328) @0 over Xs; partial @115200, fs @116032
//   over the dead G region.
// Phases: {stage G via global_load_lds, compute box masks} -> barrier ->
//   {conv1+pool sweep BOTH halves -> Xs in LDS (verbatim round-4 conv1
//   sweep, LDS dest)} -> barrier -> {acc=0; conv2 taps h=0,1 — verbatim
//   round-0 tap loop, base +h*57600} -> {pool2+mean+fc epilogue, verbatim}.
// acc liveness starts AFTER the sweep barrier — disjoint from sweep temps.
__global__ __launch_bounds__(512, 2) void fusedfull_kernel(
    const float* __restrict__ bboxes,   // [16][32][4]
    const int*   __restrict__ pairs,    // [16][64][2]
    const unsigned short* __restrict__ Gt,   // [12288] bf16
    const float* __restrict__ b1,       // [64]
    const unsigned short* __restrict__ Wr,   // [2][32][800] bf16
    const float* __restrict__ b2,       // [32]
    const float* __restrict__ fcw,      // [512][32]
    const float* __restrict__ fcb,      // [512]
    float* __restrict__ out)            // [1024][512]
{
  extern __shared__ char smem[];
  float* partial = (float*)(smem + 115200);
  float* fs      = (float*)(smem + 116032);
  float* Cout    = (float*)smem;

  const int n = blockIdx.x, t = threadIdx.x;
  const int lane = t & 63, wv = t >> 6;
  const int q = lane >> 4, ln = lane & 15;
  const int cnt = (wv < 3) ? 6 : 5;     // nt = wv + it*8 < 43

  // ---- stage G-LUT: 24576 B = 1536 x 16B, direct global->LDS @115200 ----
  {
    const char* gsrc = (const char*)Gt;
    #pragma unroll
    for (int k = 0; k < 3; k++) {
      int ci = k * 512 + t;
      __builtin_amdgcn_global_load_lds(
          (const __attribute__((address_space(1))) unsigned int*)(gsrc + ci * 16),
          (__attribute__((address_space(3))) unsigned int*)(smem + 115200 + ci * 16),
          16, 0, 0);
    }
  }

  // ---- box pair -> indicator bitmasks (lane = coordinate) ----
  u64 ixs[2], iys[2];
  {
    const int bb = n >> 6, rr_ = n & 63;
    const int p0 = pairs[(bb * 64 + rr_) * 2 + 0];
    const int p1 = pairs[(bb * 64 + rr_) * 2 + 1];
    const float* A  = bboxes + (bb * 32 + p0) * 4;
    const float* Bq = bboxes + (bb * 32 + p1) * 4;
    const float ax1 = A[0],  ay1 = A[1],  ax2 = A[2],  ay2 = A[3];
    const float cx1 = Bq[0], cy1 = Bq[1], cx2 = Bq[2], cy2 = Bq[3];
    const float ux1 = fminf(ax1, cx1), uy1 = fminf(ay1, cy1);
    const float ux2 = fmaxf(ax2, cx2), uy2 = fmaxf(ay2, cy2);
    const float uw = fmaxf(ux2 - ux1, 1e-6f), uh = fmaxf(uy2 - uy1, 1e-6f);
    const float g = (float)lane + 0.5f;
    {
      float X1 = (ax1 - ux1) / uw * 64.f, X2 = (ax2 - ux1) / uw * 64.f;
      float Y1 = (ay1 - uy1) / uh * 64.f, Y2 = (ay2 - uy1) / uh * 64.f;
      ixs[0] = __ballot(g >= X1 && g <= X2);
      iys[0] = __ballot(g >= Y1 && g <= Y2);
    }
    {
      float X1 = (cx1 - ux1) / uw * 64.f, X2 = (cx2 - ux1) / uw * 64.f;
      float Y1 = (cy1 - uy1) / uh * 64.f, Y2 = (cy2 - uy1) / uh * 64.f;
      ixs[1] = __ballot(g >= X1 && g <= X2);
      iys[1] = __ballot(g >= Y1 && g <= Y2);
    }
  }
  __syncthreads();   // G resident (vmcnt drained by barrier semantics)

  // ---- conv1+pool sweep, BOTH halves (verbatim round-4 sweep, LDS dest) ----
  {
    const int cg = t & 7, cgo = cg * 16, pr = t >> 3;
    const int hW = cg >> 2;
    float b1v[8];
    #pragma unroll
    for (int i = 0; i < 8; i++) b1v[i] = b1[cg * 8 + i];
    for (int pass = 0; pass < 15; pass++) {
      int pix = pr + (pass << 6);
      if (pix < 900) {
        int qy = pix / 30, qx = pix - qy * 30;
        int cb[2][2], ja_[2][2], jb_[2][2];
        #pragma unroll
        for (int ch = 0; ch < 2; ch++) {
          #pragma unroll
          for (int dy = 0; dy < 2; dy++) {
            unsigned m = (unsigned)(iys[ch] >> (2 * qy + dy)) & 31u;
            int ia = __ffs((int)m) - 1; if (ia < 0) ia = 0;
            int ib = 31 - __clz((int)(m | 1u));
            int cls = m ? (((ib * (ib + 1)) >> 1) + ia + 1) : 0;
            cb[ch][dy] = 115200 + (ch * 16 + cls) * 768 + cgo;
          }
          #pragma unroll
          for (int dx = 0; dx < 2; dx++) {
            unsigned mx = (unsigned)(ixs[ch] >> (2 * qx + dx)) & 31u;
            int ja = __ffs((int)mx) - 1; if (ja < 0) ja = 0;
            int jbp = mx ? (32 - __clz((int)mx)) : 0;
            ja_[ch][dx] = ja * 128; jb_[ch][dx] = jbp * 128;
          }
        }
        float V[8];
        #pragma unroll
        for (int dy = 0; dy < 2; dy++) {
          #pragma unroll
          for (int dx = 0; dx < 2; dx++) {
            float S[8] = {0, 0, 0, 0, 0, 0, 0, 0};
            #pragma unroll
            for (int ch = 0; ch < 2; ch++) {
              uint4 z = *(const uint4*)(smem + cb[ch][dy] + jb_[ch][dx]);
              uint4 a = *(const uint4*)(smem + cb[ch][dy] + ja_[ch][dx]);
              bacc(z, a, S);
            }
            #pragma unroll
            for (int k = 0; k < 8; k++)
              V[k] = (dy == 0 && dx == 0) ? S[k] : fmaxf(V[k], S[k]);
          }
        }
        uint4 pk;
        unsigned* pkp = &pk.x;
        #pragma unroll
        for (int k = 0; k < 4; k++) {
          unsigned lo = (unsigned)f2bf_rne(V[2 * k]     + b1v[2 * k]);
          unsigned hi = (unsigned)f2bf_rne(V[2 * k + 1] + b1v[2 * k + 1]);
          pkp[k] = lo | (hi << 16);
        }
        int slot = ((cg & 3) + pix) & 3;   // matches tap read (q+ps)&3
        *(uint4*)(smem + hW * 57600 + pix * 64 + slot * 16) = pk;
      }
    }
  }
  __syncthreads();   // Xs (both halves) ready; sweep temps now dead

  // ---- psB (acc-phase-local) ----
  int psB[6];
  #pragma unroll
  for (int it = 0; it < 6; it++) {
    int nt = wv + it * 8;
    int p = nt * 16 + ln; if (p > 675) p = 675;
    int y = p / 26, x = p - y * 26;
    psB[it] = (nt < 43) ? (y * 30 + x) : 0;
  }

  v4f acc[6][2];
  #pragma unroll
  for (int it = 0; it < 6; it++) { acc[it][0] = (v4f)0.f; acc[it][1] = (v4f)0.f; }

  // ---- conv2 taps: VERBATIM round-0 structure, base +h*57600 ----
  for (int h = 0; h < 2; h++) {
    const int xb = h * 57600;
    const unsigned short* pA0 = Wr + h * 25600 + ln * 800 + q * 8;
    const unsigned short* pA1 = pA0 + 16 * 800;
    for (int i = 0; i < 5; i++) {      // filter row
      #pragma unroll
      for (int j = 0; j < 5; j++) {    // filter col; tap = one MFMA k-step
        const int tap = i * 5 + j;
        v8s a0 = *(const v8s*)(pA0 + tap * 32);
        v8s a1 = *(const v8s*)(pA1 + tap * 32);
        #pragma unroll
        for (int it = 0; it < 6; it++) {
          if (it < cnt) {
            int ps = psB[it] + i * 30 + j;
            int addr = xb + (ps << 6) + (((q + ps) & 3) << 4);
            v8s b = *(const v8s*)(smem + addr);
            acc[it][0] = __builtin_amdgcn_mfma_f32_16x16x32_bf16(a0, b, acc[it][0], 0, 0, 0);
            acc[it][1] = __builtin_amdgcn_mfma_f32_16x16x32_bf16(a1, b, acc[it][1], 0, 0, 0);
          }
        }
      }
    }
  }

  // ---- per m-half, pool2 + mean + bias -> fs[32] ----
  #pragma unroll
  for (int mt = 0; mt < 2; mt++) {
    __syncthreads();               // taps/prior-Cout readers done
    #pragma unroll
    for (int it = 0; it < 6; it++) {
      if (it < cnt) {
        int p = (wv + it * 8) * 16 + ln; if (p > 675) p = 675;
        #pragma unroll
        for (int r = 0; r < 4; r++)
          Cout[(q * 4 + r) * 677 + p] = acc[it][mt][r];
      }
    }
    __syncthreads();
    if (t < 208) {
      int c = t & 15, py = t >> 4;
      const float* r0 = Cout + c * 677 + (2 * py) * 26;
      const float* r1 = r0 + 26;
      float s = 0.f;
      #pragma unroll
      for (int px = 0; px < 13; px++) {
        float m0 = fmaxf(r0[2 * px], r0[2 * px + 1]);
        float m1 = fmaxf(r1[2 * px], r1[2 * px + 1]);
        s += fmaxf(m0, m1);
      }
      partial[t] = s;
    }
    __syncthreads();
    if (t < 16) {
      float s = 0.f;
      #pragma unroll
      for (int k = 0; k < 13; k++) s += partial[k * 16 + t];
      fs[mt * 16 + t] = s * (1.f / 169.f) + b2[mt * 16 + t];
    }
  }
  __syncthreads();

  // ---- fc (512 outs, thread t -> out column t), relu ----
  {
    const float* wrow = fcw + t * 32;
    float d = 0.f;
    #pragma unroll
    for (int k = 0; k < 32; k++) d += wrow[k] * fs[k];
    out[(u64)n * 512 + t] = fmaxf(d + fcb[t], 0.f);
  }
}

// ============================================================================
// FALLBACK PATH (tiny ws): round-7 fused kernel, 409 us.
// ============================================================================

__global__ __launch_bounds__(256) void prepack(
    const float* __restrict__ w1, const float* __restrict__ w2,
    unsigned short* __restrict__ Wr, unsigned short* __restrict__ Gt) {
  int idx = blockIdx.x * 256 + threadIdx.x;
  if (idx < 51200) {
    int c = idx / 1600, rem = idx - c * 1600;
    int ch = rem & 63, tap = rem >> 6;
    Wr[idx] = f2bf_rne(w2[(c * 64 + ch) * 25 + tap]);
  } else if (idx < 51200 + 12288) {
    int e = idx - 51200;
    int ch = e / 6144, r = e - ch * 6144;
    int cls = r / 384, r2 = r - cls * 384;
    int j = r2 / 64, cout = r2 - j * 64;
    float v = 0.f;
    if (cls > 0) {
      int ia = 0, ib = 0;
      for (int bb = 0; bb < 5; bb++) {
        int base = (bb * (bb + 1)) / 2 + 1;
        if (cls >= base && cls <= base + bb) { ib = bb; ia = cls - base; }
      }
      for (int i = ia; i <= ib; i++)
        for (int jj = 0; jj < j; jj++)
          v += w1[(cout * 2 + ch) * 25 + i * 5 + jj];
    }
    Gt[e] = f2bf_rne(v);
  }
}

__global__ __launch_bounds__(512, 2) void fused_kernel(
    const float* __restrict__ bboxes, const int* __restrict__ pairs,
    const unsigned short* __restrict__ Gt, const float* __restrict__ b1,
    const unsigned short* __restrict__ Wr, const float* __restrict__ b2,
    const float* __restrict__ fcw, const float* __restrict__ fcb,
    float* __restrict__ out)
{
  extern __shared__ char smem[];
  float* partial = (float*)(smem + 146976);
  float* fs      = (float*)(smem + 147808);
  float* Cout    = (float*)smem;

  const int n = blockIdx.x, t = threadIdx.x;
  const int lane = t & 63, wv = t >> 6;
  const int q = lane >> 4, ln = lane & 15;

  {
    const uint4* src = (const uint4*)Gt;
    uint4* dst = (uint4*)(smem + 122400);
    #pragma unroll
    for (int i = 0; i < 3; i++) dst[t + i * 512] = src[t + i * 512];
  }
  const int bb = n >> 6, rr_ = n & 63;
  const int p0 = pairs[(bb * 64 + rr_) * 2 + 0];
  const int p1 = pairs[(bb * 64 + rr_) * 2 + 1];
  const float* A  = bboxes + (bb * 32 + p0) * 4;
  const float* Bq = bboxes + (bb * 32 + p1) * 4;
  const float ax1 = A[0],  ay1 = A[1],  ax2 = A[2],  ay2 = A[3];
  const float cx1 = Bq[0], cy1 = Bq[1], cx2 = Bq[2], cy2 = Bq[3];
  const float ux1 = fminf(ax1, cx1), uy1 = fminf(ay1, cy1);
  const float ux2 = fmaxf(ax2, cx2), uy2 = fmaxf(ay2, cy2);
  const float uw = fmaxf(ux2 - ux1, 1e-6f), uh = fmaxf(uy2 - uy1, 1e-6f);
  const float g = (float)lane + 0.5f;
  u64 ixs[2], iys[2];
  {
    float X1 = (ax1 - ux1) / uw * 64.f, X2 = (ax2 - ux1) / uw * 64.f;
    float Y1 = (ay1 - uy1) / uh * 64.f, Y2 = (ay2 - uy1) / uh * 64.f;
    ixs[0] = __ballot(g >= X1 && g <= X2);
    iys[0] = __ballot(g >= Y1 && g <= Y2);
  }
  {
    float X1 = (cx1 - ux1) / uw * 64.f, X2 = (cx2 - ux1) / uw * 64.f;
    float Y1 = (cy1 - uy1) / uh * 64.f, Y2 = (cy2 - uy1) / uh * 64.f;
    ixs[1] = __ballot(g >= X1 && g <= X2);
    iys[1] = __ballot(g >= Y1 && g <= Y2);
  }
  __syncthreads();

  {
    const int cg = t & 7, cgo = cg * 16, pr = t >> 3;
    float b1v[8];
    #pragma unroll
    for (int i = 0; i < 8; i++) b1v[i] = b1[cg * 8 + i];
    for (int pass = 0; pass < 15; pass++) {
      int pix = pr + (pass << 6);
      if (pix < 900) {
        int qy = pix / 30, qx = pix - qy * 30;
        int cb[2][2], ja_[2][2], jb_[2][2];
        #pragma unroll
        for (int ch = 0; ch < 2; ch++) {
          #pragma unroll
          for (int dy = 0; dy < 2; dy++) {
            unsigned m = (unsigned)(iys[ch] >> (2 * qy + dy)) & 31u;
            int ia = __ffs((int)m) - 1; if (ia < 0) ia = 0;
            int ib = 31 - __clz((int)(m | 1u));
            int cls = m ? (((ib * (ib + 1)) >> 1) + ia + 1) : 0;
            cb[ch][dy] = 122400 + (ch * 16 + cls) * 768 + cgo;
          }
          #pragma unroll
          for (int dx = 0; dx < 2; dx++) {
            unsigned mx = (unsigned)(ixs[ch] >> (2 * qx + dx)) & 31u;
            int ja = __ffs((int)mx) - 1; if (ja < 0) ja = 0;
            int jbp = mx ? (32 - __clz((int)mx)) : 0;
            ja_[ch][dx] = ja * 128; jb_[ch][dx] = jbp * 128;
          }
        }
        float V[8];
        #pragma unroll
        for (int dy = 0; dy < 2; dy++) {
          #pragma unroll
          for (int dx = 0; dx < 2; dx++) {
            float S[8] = {0, 0, 0, 0, 0, 0, 0, 0};
            #pragma unroll
            for (int ch = 0; ch < 2; ch++) {
              uint4 z = *(const uint4*)(smem + cb[ch][dy] + jb_[ch][dx]);
              uint4 a = *(const uint4*)(smem + cb[ch][dy] + ja_[ch][dx]);
              bacc(z, a, S);
            }
            #pragma unroll
            for (int k = 0; k < 8; k++)
              V[k] = (dy == 0 && dx == 0) ? S[k] : fmaxf(V[k], S[k]);
          }
        }
        unsigned dws[4];
        #pragma unroll
        for (int k = 0; k < 4; k++) {
          unsigned lo = (unsigned)f2bf_rne(V[2 * k]     + b1v[2 * k]);
          unsigned hi = (unsigned)f2bf_rne(V[2 * k + 1] + b1v[2 * k + 1]);
          dws[k] = lo | (hi << 16);
        }
        uint2 s0; s0.x = dws[0]; s0.y = dws[1];
        uint2 s1; s1.x = dws[2]; s1.y = dws[3];
        *(uint2*)(smem + pix * 136 + cgo) = s0;
        *(uint2*)(smem + pix * 136 + cgo + 8) = s1;
      }
    }
  }
  __syncthreads();

  v4f acc[6][2];
  int pclamp[6], baseB[6];
  int cnt = 0;
  #pragma unroll
  for (int it = 0; it < 6; it++) {
    int nt = wv + it * 8;
    if (nt < 43) {
      int p = nt * 16 + ln; if (p > 675) p = 675;
      pclamp[it] = p;
      int y = p / 26, x = p - y * 26;
      baseB[it] = (y * 30 + x) * 136 + q * 16;
      cnt = it + 1;
    } else { pclamp[it] = 0; baseB[it] = 0; }
    acc[it][0] = (v4f)0.f; acc[it][1] = (v4f)0.f;
  }
  const unsigned short* pA0 = Wr + ln * 1600 + q * 8;
  const unsigned short* pA1 = pA0 + 16 * 1600;
  for (int i5 = 0; i5 < 5; i5++) {
    const int ro = i5 * 4080;
    #pragma unroll
    for (int jt = 0; jt < 5; jt++) {
      #pragma unroll
      for (int hh = 0; hh < 2; hh++) {
        const int s = (i5 * 5 + jt) * 2 + hh;
        v8s a0 = *(const v8s*)(pA0 + s * 32);
        v8s a1 = *(const v8s*)(pA1 + s * 32);
        const int off = ro + jt * 136 + hh * 64;
        #pragma unroll
        for (int it = 0; it < 6; it++) {
          if (it < cnt) {
            uint2 lo = *(const uint2*)(smem + (baseB[it] + off));
            uint2 hi = *(const uint2*)(smem + (baseB[it] + off + 8));
            uint4 bv; bv.x = lo.x; bv.y = lo.y; bv.z = hi.x; bv.w = hi.y;
            v8s b = __builtin_bit_cast(v8s, bv);
            acc[it][0] = __builtin_amdgcn_mfma_f32_16x16x32_bf16(a0, b, acc[it][0], 0, 0, 0);
            acc[it][1] = __builtin_amdgcn_mfma_f32_16x16x32_bf16(a1, b, acc[it][1], 0, 0, 0);
          }
        }
      }
    }
  }
  #pragma unroll
  for (int mt = 0; mt < 2; mt++) {
    __syncthreads();
    #pragma unroll
    for (int it = 0; it < 6; it++) {
      if (it < cnt) {
        #pragma unroll
        for (int r = 0; r < 4; r++)
          Cout[(q * 4 + r) * 677 + pclamp[it]] = acc[it][mt][r];
      }
    }
    __syncthreads();
    if (t < 208) {
      int c = t & 15, py = t >> 4;
      const float* r0 = Cout + c * 677 + (2 * py) * 26;
      const float* r1 = r0 + 26;
      float s = 0.f;
      #pragma unroll
      for (int px = 0; px < 13; px++) {
        float m0 = fmaxf(r0[2 * px], r0[2 * px + 1]);
        float m1 = fmaxf(r1[2 * px], r1[2 * px + 1]);
        s += fmaxf(m0, m1);
      }
      partial[t] = s;
    }
    __syncthreads();
    if (t < 16) {
      float s = 0.f;
      #pragma unroll
      for (int k = 0; k < 13; k++) s += partial[k * 16 + t];
      fs[mt * 16 + t] = s * (1.f / 169.f) + b2[mt * 16 + t];
    }
  }
  __syncthreads();
  {
    const float* wrow = fcw + t * 32;
    float d = 0.f;
    #pragma unroll
    for (int k = 0; k < 32; k++) d += wrow[k] * fs[k];
    out[(u64)n * 512 + t] = fmaxf(d + fcb[t], 0.f);
  }
}

extern "C" void kernel_launch(void* const* d_in, const int* in_sizes, int n_in,
                              void* d_out, int out_size, void* d_ws, size_t ws_size,
                              hipStream_t stream) {
  const float* bboxes = (const float*)d_in[0];
  // d_in[1] = num_obj, d_in[2] = num_relation: constants, unused by the math
  const int*   pairs  = (const int*)  d_in[3];
  const float* w1     = (const float*)d_in[4];
  const float* b1     = (const float*)d_in[5];
  const float* w2     = (const float*)d_in[6];
  const float* b2     = (const float*)d_in[7];
  const float* fcw    = (const float*)d_in[8];
  const float* fcb    = (const float*)d_in[9];
  float* out = (float*)d_out;

  if (ws_size >= 126976) {
    // fast path: prepack2 (Wr 102400 B @0, Gt 24576 B @102400) -> fusedfull
    unsigned short* Wr = (unsigned short*)d_ws;
    unsigned short* Gt = (unsigned short*)((char*)d_ws + 102400);
    prepack2<<<124, 512, 0, stream>>>(w1, w2, Wr, Gt);
    fusedfull_kernel<<<1024, 512, 139776, stream>>>(bboxes, pairs, Gt, b1, Wr,
                                                    b2, fcw, fcb, out);
  } else {
    // fallback: round-7 fused path
    unsigned short* Wr = (unsigned short*)d_ws;                      // 102400 B
    unsigned short* Gt = (unsigned short*)((char*)d_ws + 102400);    //  24576 B
    prepack<<<248, 256, 0, stream>>>(w1, w2, Wr, Gt);
    fused_kernel<<<1024, 512, 147936, stream>>>(bboxes, pairs, Gt, b1, Wr, b2,
                                                fcw, fcb, out);
  }
}

// Round 7
// 227.361 us; speedup vs baseline: 1.7708x; 1.7708x over previous
//
#include <hip/hip_runtime.h>
#include <stdint.h>

typedef unsigned long long u64;
typedef short v8s __attribute__((ext_vector_type(8)));   // 8 bf16 (4 VGPRs) — MFMA A/B frag
typedef float v4f __attribute__((ext_vector_type(4)));   // MFMA C/D frag

__device__ __forceinline__ unsigned short f2bf_rne(float f) {
  union { float f; unsigned u; } c; c.f = f;
  unsigned u = c.u;
  u += 0x7fffu + ((u >> 16) & 1u);   // round-to-nearest-even
  return (unsigned short)(u >> 16);
}

// unpack bf16x8 pair (z,a), accumulate S[k] += z[k] - a[k]
__device__ __forceinline__ void bacc(uint4 z, uint4 a, float* S) {
  const unsigned* zp = &z.x;
  const unsigned* ap = &a.x;
  #pragma unroll
  for (int k = 0; k < 4; k++) {
    unsigned zu = zp[k], au = ap[k];
    S[2 * k]     += __uint_as_float(zu << 16)         - __uint_as_float(au << 16);
    S[2 * k + 1] += __uint_as_float(zu & 0xffff0000u) - __uint_as_float(au & 0xffff0000u);
  }
}

// ============================================================================
// FAST PATH (ws >= 118 MB): prepack_g + conv1 + conv2 (round-4 structure).
//
// Register-cliff ledger (rounds 1-6): the conv2 tap loop spills scratch on
// ANY added VALU/live value (r1 bfr[6], r2 batch-3, r3 one extra shift: each
// +50-80MB FETCH/WRITE, +15-22us). Fusion spills even at (512,2) with 256-reg
// budget (r5: 271us, r6: 341us, WRITE ~270MB) — compiler hoisting creates
// pressure peaks far above source-level liveness. Structure is frozen as
// round-4's 3-kernel pipeline.
//
// THIS round: kill conv2's 4-way LDS bank conflict (9.93M cyc/dispatch) by
// LAYOUT, not address math: LDS pixel stride 80B (64B data + 16B pad).
// Bank-cluster(ps,q) = (5*ps+q) mod 8; 5 coprime 8 -> 16 consecutive ps
// cover all 8 clusters twice = 2-way = free (m136). Tap address is
// psB80[it] + i*2400 + j*80 — FEWER ops and temps than round-0's
// (ps<<6)+(((q+ps)&3)<<4). Global XsG stays 64B/pixel (ws unchanged);
// the 80-stride LDS image is built by per-lane-source global_load_lds
// (lds unit m <-> p=m/5, sl=m%5; sl==4 pad lanes re-load slot 0, full exec).
// Spill tripwire: conv2 WRITE_SIZE > 25 MB -> revert to round-4 artifact.
// ============================================================================

// prepack_g: G-LUT from w1 only — computed once (not per conv1 block).
__global__ __launch_bounds__(512) void prepack_g(
    const float* __restrict__ w1,       // [64][2][5][5]
    unsigned short* __restrict__ Gt)    // [12288] bf16
{
  int e = blockIdx.x * 512 + threadIdx.x;   // grid 24*512 = 12288 exact
  int ch = e / 6144, r = e - ch * 6144;
  int cls = r / 384, r2 = r - cls * 384;
  int j = r2 / 64, cout = r2 - j * 64;
  float v = 0.f;
  if (cls > 0) {
    int ia = 0, ib = 0;
    #pragma unroll
    for (int bb = 0; bb < 5; bb++) {
      int base = (bb * (bb + 1)) / 2 + 1;
      if (cls >= base && cls <= base + bb) { ib = bb; ia = cls - base; }
    }
    for (int i = ia; i <= ib; i++)
      for (int jj = 0; jj < j; jj++)
        v += w1[(cout * 2 + ch) * 25 + i * 5 + jj];
  }
  Gt[e] = f2bf_rne(v);
}

// Kernel A: conv1+pool -> XsG (bf16), plus Wr packing.
// Blocks 0..1023: one image each. LDS 24576 B = G-LUT (copied from Gt).
// XsG layout: img*115200 + h*57600 + pix*64 + (cg&3)*16  (h = cg>>2).
// Slot is now PLAIN (cg&3): conv2's conflict fix lives in its LDS stride,
// so no store-side rotation is needed. 8 lanes fill two 64B lines/pixel.
// Blocks 1024..1048: pack conv2 weights Wr[h*25600 + c*800 + tap*32 + chh].
__global__ __launch_bounds__(512, 8) void conv1_kernel(
    const float* __restrict__ bboxes,   // [16][32][4]
    const int*   __restrict__ pairs,    // [16][64][2]
    const unsigned short* __restrict__ Gt,  // [12288] bf16 (prepack_g)
    const float* __restrict__ b1,       // [64]
    const float* __restrict__ w2,       // [32][64][5][5]
    unsigned short* __restrict__ XsG,   // [1024][2][900][32] bf16
    unsigned short* __restrict__ Wr)    // [2][32][800] bf16
{
  const int t = threadIdx.x;
  if (blockIdx.x >= 1024) {             // Wr-pack blocks
    int bb2 = blockIdx.x - 1024;
    #pragma unroll
    for (int r = 0; r < 4; r++) {
      int idx = bb2 * 2048 + r * 512 + t;   // < 51200
      int c = idx / 1600, rem = idx - c * 1600;
      int h = rem / 800, r2 = rem - h * 800;
      int tap = r2 >> 5, chh = r2 & 31;
      Wr[h * 25600 + c * 800 + r2] =
          f2bf_rne(w2[(c * 64 + h * 32 + chh) * 25 + tap]);
    }
    return;
  }
  extern __shared__ char smem[];

  const int n = blockIdx.x;
  const int lane = t & 63;

  // ---- G-LUT: straight copy from Gt (24576 B = 1536 uint4) ----
  {
    const uint4* src = (const uint4*)Gt;
    uint4* dst = (uint4*)smem;
    #pragma unroll
    for (int i = 0; i < 3; i++) dst[t + i * 512] = src[t + i * 512];
  }

  // ---- box pair -> indicator bitmasks (lane = coordinate) ----
  const int bb = n >> 6, rr_ = n & 63;
  const int p0 = pairs[(bb * 64 + rr_) * 2 + 0];
  const int p1 = pairs[(bb * 64 + rr_) * 2 + 1];
  const float* A  = bboxes + (bb * 32 + p0) * 4;
  const float* Bq = bboxes + (bb * 32 + p1) * 4;
  const float ax1 = A[0],  ay1 = A[1],  ax2 = A[2],  ay2 = A[3];
  const float cx1 = Bq[0], cy1 = Bq[1], cx2 = Bq[2], cy2 = Bq[3];
  const float ux1 = fminf(ax1, cx1), uy1 = fminf(ay1, cy1);
  const float ux2 = fmaxf(ax2, cx2), uy2 = fmaxf(ay2, cy2);
  const float uw = fmaxf(ux2 - ux1, 1e-6f), uh = fmaxf(uy2 - uy1, 1e-6f);
  const float g = (float)lane + 0.5f;
  u64 ixs[2], iys[2];
  {
    float X1 = (ax1 - ux1) / uw * 64.f, X2 = (ax2 - ux1) / uw * 64.f;
    float Y1 = (ay1 - uy1) / uh * 64.f, Y2 = (ay2 - uy1) / uh * 64.f;
    ixs[0] = __ballot(g >= X1 && g <= X2);
    iys[0] = __ballot(g >= Y1 && g <= Y2);
  }
  {
    float X1 = (cx1 - ux1) / uw * 64.f, X2 = (cx2 - ux1) / uw * 64.f;
    float Y1 = (cy1 - uy1) / uh * 64.f, Y2 = (cy2 - uy1) / uh * 64.f;
    ixs[1] = __ballot(g >= X1 && g <= X2);
    iys[1] = __ballot(g >= Y1 && g <= Y2);
  }
  __syncthreads();   // G resident

  // ---- conv1+pool sweep: item = (pixel, cout-group), barrier-free ----
  const int cg = t & 7, cgo = cg * 16, pr = t >> 3;
  const int hW = cg >> 2;
  float b1v[8];
  #pragma unroll
  for (int i = 0; i < 8; i++) b1v[i] = b1[cg * 8 + i];
  char* const Xbase = (char*)XsG + (u64)n * 115200 + hW * 57600;
  for (int pass = 0; pass < 15; pass++) {
    int pix = pr + (pass << 6);
    if (pix < 900) {
      int qy = pix / 30, qx = pix - qy * 30;
      int cb[2][2], ja_[2][2], jb_[2][2];
      #pragma unroll
      for (int ch = 0; ch < 2; ch++) {
        #pragma unroll
        for (int dy = 0; dy < 2; dy++) {
          unsigned m = (unsigned)(iys[ch] >> (2 * qy + dy)) & 31u;
          int ia = __ffs((int)m) - 1; if (ia < 0) ia = 0;
          int ib = 31 - __clz((int)(m | 1u));
          int cls = m ? (((ib * (ib + 1)) >> 1) + ia + 1) : 0;
          cb[ch][dy] = (ch * 16 + cls) * 768 + cgo;
        }
        #pragma unroll
        for (int dx = 0; dx < 2; dx++) {
          unsigned mx = (unsigned)(ixs[ch] >> (2 * qx + dx)) & 31u;
          int ja = __ffs((int)mx) - 1; if (ja < 0) ja = 0;
          int jbp = mx ? (32 - __clz((int)mx)) : 0;
          ja_[ch][dx] = ja * 128; jb_[ch][dx] = jbp * 128;
        }
      }
      float V[8];
      #pragma unroll
      for (int dy = 0; dy < 2; dy++) {
        #pragma unroll
        for (int dx = 0; dx < 2; dx++) {
          float S[8] = {0, 0, 0, 0, 0, 0, 0, 0};
          #pragma unroll
          for (int ch = 0; ch < 2; ch++) {
            uint4 z = *(const uint4*)(smem + cb[ch][dy] + jb_[ch][dx]);
            uint4 a = *(const uint4*)(smem + cb[ch][dy] + ja_[ch][dx]);
            bacc(z, a, S);
          }
          #pragma unroll
          for (int k = 0; k < 8; k++)
            V[k] = (dy == 0 && dx == 0) ? S[k] : fmaxf(V[k], S[k]);
        }
      }
      uint4 pk;
      unsigned* pkp = &pk.x;
      #pragma unroll
      for (int k = 0; k < 4; k++) {
        unsigned lo = (unsigned)f2bf_rne(V[2 * k]     + b1v[2 * k]);
        unsigned hi = (unsigned)f2bf_rne(V[2 * k + 1] + b1v[2 * k + 1]);
        pkp[k] = lo | (hi << 16);
      }
      *(uint4*)(Xbase + pix * 64 + (cg & 3) * 16) = pk;   // plain slot
    }
  }
}

// Kernel B: conv2 implicit-GEMM + pool + mean + fc. One block/image.
// LDS 74688 B -> 2 blocks/CU:
//   Xs half @0: 900 px * 80 B (64B data + 16B pad) = 72000
//   staging tail pad [72000,73728) (units 4500..4607, garbage, never read)
//   partial @73728 (832), fs @74560 (128). Cout (43328) aliases Xs.
// Staging: 9 full 512-thread passes of global_load_lds; unit m -> p=m/5,
// sl=m%5; src = Xg + p*64 + (sl&3)*16 (pad lanes re-read slot 0, full exec;
// per-lane SOURCE is allowed, LDS dest stays base+lane*16 linear).
// Tap read: addr = psB80[it] + i*2400 + j*80 — bank-cluster (5*ps+q)%8,
// 2-way for 16 consecutive ps (free). Fewer VALU/temps than round-0.
// Tap loop register discipline unchanged: one B-fragment live at a time.
__global__ __launch_bounds__(512, 4) void conv2_kernel(
    const unsigned short* __restrict__ XsG,
    const unsigned short* __restrict__ Wr,   // [2][32][800] bf16
    const float* __restrict__ b2,            // [32]
    const float* __restrict__ fcw,           // [512][32]
    const float* __restrict__ fcb,           // [512]
    float* __restrict__ out)                 // [1024][512]
{
  extern __shared__ char smem[];
  float* partial = (float*)(smem + 73728);
  float* fs      = (float*)(smem + 74560);
  float* Cout    = (float*)smem;

  const int n = blockIdx.x, t = threadIdx.x;
  const int lane = t & 63, wv = t >> 6;
  const int q = lane >> 4, ln = lane & 15;

  // n-tiles of 16 pixels, 43 tiles over 676 outputs
  v4f acc[6][2];
  int psB80[6];
  int cnt = 0;
  #pragma unroll
  for (int it = 0; it < 6; it++) {
    int nt = wv + it * 8;
    if (nt < 43) {
      int p = nt * 16 + ln; if (p > 675) p = 675;   // dup-compute pad lanes
      int y = p / 26, x = p - y * 26;
      psB80[it] = (y * 30 + x) * 80 + q * 16;
      cnt = it + 1;
    } else { psB80[it] = q * 16; }
    acc[it][0] = (v4f)0.f; acc[it][1] = (v4f)0.f;
  }

  const char* Xg = (const char*)XsG + (u64)n * 115200;
  for (int h = 0; h < 2; h++) {
    if (h) __syncthreads();            // all h=0 fragment reads done
    // stage: 4608 16B units (4500 real + 108 tail pad), 9 full passes
    {
      const char* src = Xg + h * 57600;
      #pragma unroll
      for (int k = 0; k < 9; k++) {
        int m = k * 512 + t;
        int p = m / 5;
        int sl = (m - p * 5) & 3;      // pad unit (m%5==4) re-reads slot 0
        __builtin_amdgcn_global_load_lds(
            (const __attribute__((address_space(1))) unsigned int*)(src + p * 64 + sl * 16),
            (__attribute__((address_space(3))) unsigned int*)(smem + m * 16),
            16, 0, 0);
      }
    }
    __syncthreads();                   // staging drained (vmcnt before barrier)

    const unsigned short* pA0 = Wr + h * 25600 + ln * 800 + q * 8;
    const unsigned short* pA1 = pA0 + 16 * 800;
    for (int i = 0; i < 5; i++) {      // filter row
      const int ib80 = i * 2400;       // i*30 pixels * 80 B
      #pragma unroll
      for (int j = 0; j < 5; j++) {    // filter col; tap covers 32 ch = one MFMA k-step
        const int tap = i * 5 + j;
        const int off = ib80 + j * 80;
        v8s a0 = *(const v8s*)(pA0 + tap * 32);
        v8s a1 = *(const v8s*)(pA1 + tap * 32);
        #pragma unroll
        for (int it = 0; it < 6; it++) {
          if (it < cnt) {
            v8s b = *(const v8s*)(smem + psB80[it] + off);
            acc[it][0] = __builtin_amdgcn_mfma_f32_16x16x32_bf16(a0, b, acc[it][0], 0, 0, 0);
            acc[it][1] = __builtin_amdgcn_mfma_f32_16x16x32_bf16(a1, b, acc[it][1], 0, 0, 0);
          }
        }
      }
    }
  }

  // ---- per m-half, pool2 + mean + bias -> fs[32] ----
  #pragma unroll
  for (int mt = 0; mt < 2; mt++) {
    __syncthreads();               // prior Xs/Cout readers done
    #pragma unroll
    for (int it = 0; it < 6; it++) {
      if (it < cnt) {
        int p = (wv + it * 8) * 16 + ln; if (p > 675) p = 675;
        #pragma unroll
        for (int r = 0; r < 4; r++)
          Cout[(q * 4 + r) * 677 + p] = acc[it][mt][r];
      }
    }
    __syncthreads();
    if (t < 208) {
      int c = t & 15, py = t >> 4;
      const float* r0 = Cout + c * 677 + (2 * py) * 26;
      const float* r1 = r0 + 26;
      float s = 0.f;
      #pragma unroll
      for (int px = 0; px < 13; px++) {
        float m0 = fmaxf(r0[2 * px], r0[2 * px + 1]);
        float m1 = fmaxf(r1[2 * px], r1[2 * px + 1]);
        s += fmaxf(m0, m1);
      }
      partial[t] = s;
    }
    __syncthreads();
    if (t < 16) {
      float s = 0.f;
      #pragma unroll
      for (int k = 0; k < 13; k++) s += partial[k * 16 + t];
      fs[mt * 16 + t] = s * (1.f / 169.f) + b2[mt * 16 + t];
    }
  }
  __syncthreads();

  // ---- fc (512 outs, thread t -> out column t), relu ----
  {
    const float* wrow = fcw + t * 32;
    float d = 0.f;
    #pragma unroll
    for (int k = 0; k < 32; k++) d += wrow[k] * fs[k];
    out[(u64)n * 512 + t] = fmaxf(d + fcb[t], 0.f);
  }
}

// ============================================================================
// FALLBACK PATH (tiny ws): round-7 fused kernel, 409 us.
// ============================================================================

__global__ __launch_bounds__(256) void prepack(
    const float* __restrict__ w1, const float* __restrict__ w2,
    unsigned short* __restrict__ Wr, unsigned short* __restrict__ Gt) {
  int idx = blockIdx.x * 256 + threadIdx.x;
  if (idx < 51200) {
    int c = idx / 1600, rem = idx - c * 1600;
    int ch = rem & 63, tap = rem >> 6;
    Wr[idx] = f2bf_rne(w2[(c * 64 + ch) * 25 + tap]);
  } else if (idx < 51200 + 12288) {
    int e = idx - 51200;
    int ch = e / 6144, r = e - ch * 6144;
    int cls = r / 384, r2 = r - cls * 384;
    int j = r2 / 64, cout = r2 - j * 64;
    float v = 0.f;
    if (cls > 0) {
      int ia = 0, ib = 0;
      for (int bb = 0; bb < 5; bb++) {
        int base = (bb * (bb + 1)) / 2 + 1;
        if (cls >= base && cls <= base + bb) { ib = bb; ia = cls - base; }
      }
      for (int i = ia; i <= ib; i++)
        for (int jj = 0; jj < j; jj++)
          v += w1[(cout * 2 + ch) * 25 + i * 5 + jj];
    }
    Gt[e] = f2bf_rne(v);
  }
}

__global__ __launch_bounds__(512, 2) void fused_kernel(
    const float* __restrict__ bboxes, const int* __restrict__ pairs,
    const unsigned short* __restrict__ Gt, const float* __restrict__ b1,
    const unsigned short* __restrict__ Wr, const float* __restrict__ b2,
    const float* __restrict__ fcw, const float* __restrict__ fcb,
    float* __restrict__ out)
{
  extern __shared__ char smem[];
  float* partial = (float*)(smem + 146976);
  float* fs      = (float*)(smem + 147808);
  float* Cout    = (float*)smem;

  const int n = blockIdx.x, t = threadIdx.x;
  const int lane = t & 63, wv = t >> 6;
  const int q = lane >> 4, ln = lane & 15;

  {
    const uint4* src = (const uint4*)Gt;
    uint4* dst = (uint4*)(smem + 122400);
    #pragma unroll
    for (int i = 0; i < 3; i++) dst[t + i * 512] = src[t + i * 512];
  }
  const int bb = n >> 6, rr_ = n & 63;
  const int p0 = pairs[(bb * 64 + rr_) * 2 + 0];
  const int p1 = pairs[(bb * 64 + rr_) * 2 + 1];
  const float* A  = bboxes + (bb * 32 + p0) * 4;
  const float* Bq = bboxes + (bb * 32 + p1) * 4;
  const float ax1 = A[0],  ay1 = A[1],  ax2 = A[2],  ay2 = A[3];
  const float cx1 = Bq[0], cy1 = Bq[1], cx2 = Bq[2], cy2 = Bq[3];
  const float ux1 = fminf(ax1, cx1), uy1 = fminf(ay1, cy1);
  const float ux2 = fmaxf(ax2, cx2), uy2 = fmaxf(ay2, cy2);
  const float uw = fmaxf(ux2 - ux1, 1e-6f), uh = fmaxf(uy2 - uy1, 1e-6f);
  const float g = (float)lane + 0.5f;
  u64 ixs[2], iys[2];
  {
    float X1 = (ax1 - ux1) / uw * 64.f, X2 = (ax2 - ux1) / uw * 64.f;
    float Y1 = (ay1 - uy1) / uh * 64.f, Y2 = (ay2 - uy1) / uh * 64.f;
    ixs[0] = __ballot(g >= X1 && g <= X2);
    iys[0] = __ballot(g >= Y1 && g <= Y2);
  }
  {
    float X1 = (cx1 - ux1) / uw * 64.f, X2 = (cx2 - ux1) / uw * 64.f;
    float Y1 = (cy1 - uy1) / uh * 64.f, Y2 = (cy2 - uy1) / uh * 64.f;
    ixs[1] = __ballot(g >= X1 && g <= X2);
    iys[1] = __ballot(g >= Y1 && g <= Y2);
  }
  __syncthreads();

  {
    const int cg = t & 7, cgo = cg * 16, pr = t >> 3;
    float b1v[8];
    #pragma unroll
    for (int i = 0; i < 8; i++) b1v[i] = b1[cg * 8 + i];
    for (int pass = 0; pass < 15; pass++) {
      int pix = pr + (pass << 6);
      if (pix < 900) {
        int qy = pix / 30, qx = pix - qy * 30;
        int cb[2][2], ja_[2][2], jb_[2][2];
        #pragma unroll
        for (int ch = 0; ch < 2; ch++) {
          #pragma unroll
          for (int dy = 0; dy < 2; dy++) {
            unsigned m = (unsigned)(iys[ch] >> (2 * qy + dy)) & 31u;
            int ia = __ffs((int)m) - 1; if (ia < 0) ia = 0;
            int ib = 31 - __clz((int)(m | 1u));
            int cls = m ? (((ib * (ib + 1)) >> 1) + ia + 1) : 0;
            cb[ch][dy] = 122400 + (ch * 16 + cls) * 768 + cgo;
          }
          #pragma unroll
          for (int dx = 0; dx < 2; dx++) {
            unsigned mx = (unsigned)(ixs[ch] >> (2 * qx + dx)) & 31u;
            int ja = __ffs((int)mx) - 1; if (ja < 0) ja = 0;
            int jbp = mx ? (32 - __clz((int)mx)) : 0;
            ja_[ch][dx] = ja * 128; jb_[ch][dx] = jbp * 128;
          }
        }
        float V[8];
        #pragma unroll
        for (int dy = 0; dy < 2; dy++) {
          #pragma unroll
          for (int dx = 0; dx < 2; dx++) {
            float S[8] = {0, 0, 0, 0, 0, 0, 0, 0};
            #pragma unroll
            for (int ch = 0; ch < 2; ch++) {
              uint4 z = *(const uint4*)(smem + cb[ch][dy] + jb_[ch][dx]);
              uint4 a = *(const uint4*)(smem + cb[ch][dy] + ja_[ch][dx]);
              bacc(z, a, S);
            }
            #pragma unroll
            for (int k = 0; k < 8; k++)
              V[k] = (dy == 0 && dx == 0) ? S[k] : fmaxf(V[k], S[k]);
          }
        }
        unsigned dws[4];
        #pragma unroll
        for (int k = 0; k < 4; k++) {
          unsigned lo = (unsigned)f2bf_rne(V[2 * k]     + b1v[2 * k]);
          unsigned hi = (unsigned)f2bf_rne(V[2 * k + 1] + b1v[2 * k + 1]);
          dws[k] = lo | (hi << 16);
        }
        uint2 s0; s0.x = dws[0]; s0.y = dws[1];
        uint2 s1; s1.x = dws[2]; s1.y = dws[3];
        *(uint2*)(smem + pix * 136 + cgo) = s0;
        *(uint2*)(smem + pix * 136 + cgo + 8) = s1;
      }
    }
  }
  __syncthreads();

  v4f acc[6][2];
  int pclamp[6], baseB[6];
  int cnt = 0;
  #pragma unroll
  for (int it = 0; it < 6; it++) {
    int nt = wv + it * 8;
    if (nt < 43) {
      int p = nt * 16 + ln; if (p > 675) p = 675;
      pclamp[it] = p;
      int y = p / 26, x = p - y * 26;
      baseB[it] = (y * 30 + x) * 136 + q * 16;
      cnt = it + 1;
    } else { pclamp[it] = 0; baseB[it] = 0; }
    acc[it][0] = (v4f)0.f; acc[it][1] = (v4f)0.f;
  }
  const unsigned short* pA0 = Wr + ln * 1600 + q * 8;
  const unsigned short* pA1 = pA0 + 16 * 1600;
  for (int i5 = 0; i5 < 5; i5++) {
    const int ro = i5 * 4080;
    #pragma unroll
    for (int jt = 0; jt < 5; jt++) {
      #pragma unroll
      for (int hh = 0; hh < 2; hh++) {
        const int s = (i5 * 5 + jt) * 2 + hh;
        v8s a0 = *(const v8s*)(pA0 + s * 32);
        v8s a1 = *(const v8s*)(pA1 + s * 32);
        const int off = ro + jt * 136 + hh * 64;
        #pragma unroll
        for (int it = 0; it < 6; it++) {
          if (it < cnt) {
            uint2 lo = *(const uint2*)(smem + (baseB[it] + off));
            uint2 hi = *(const uint2*)(smem + (baseB[it] + off + 8));
            uint4 bv; bv.x = lo.x; bv.y = lo.y; bv.z = hi.x; bv.w = hi.y;
            v8s b = __builtin_bit_cast(v8s, bv);
            acc[it][0] = __builtin_amdgcn_mfma_f32_16x16x32_bf16(a0, b, acc[it][0], 0, 0, 0);
            acc[it][1] = __builtin_amdgcn_mfma_f32_16x16x32_bf16(a1, b, acc[it][1], 0, 0, 0);
          }
        }
      }
    }
  }
  #pragma unroll
  for (int mt = 0; mt < 2; mt++) {
    __syncthreads();
    #pragma unroll
    for (int it = 0; it < 6; it++) {
      if (it < cnt) {
        #pragma unroll
        for (int r = 0; r < 4; r++)
          Cout[(q * 4 + r) * 677 + pclamp[it]] = acc[it][mt][r];
      }
    }
    __syncthreads();
    if (t < 208) {
      int c = t & 15, py = t >> 4;
      const float* r0 = Cout + c * 677 + (2 * py) * 26;
      const float* r1 = r0 + 26;
      float s = 0.f;
      #pragma unroll
      for (int px = 0; px < 13; px++) {
        float m0 = fmaxf(r0[2 * px], r0[2 * px + 1]);
        float m1 = fmaxf(r1[2 * px], r1[2 * px + 1]);
        s += fmaxf(m0, m1);
      }
      partial[t] = s;
    }
    __syncthreads();
    if (t < 16) {
      float s = 0.f;
      #pragma unroll
      for (int k = 0; k < 13; k++) s += partial[k * 16 + t];
      fs[mt * 16 + t] = s * (1.f / 169.f) + b2[mt * 16 + t];
    }
  }
  __syncthreads();
  {
    const float* wrow = fcw + t * 32;
    float d = 0.f;
    #pragma unroll
    for (int k = 0; k < 32; k++) d += wrow[k] * fs[k];
    out[(u64)n * 512 + t] = fmaxf(d + fcb[t], 0.f);
  }
}

extern "C" void kernel_launch(void* const* d_in, const int* in_sizes, int n_in,
                              void* d_out, int out_size, void* d_ws, size_t ws_size,
                              hipStream_t stream) {
  const float* bboxes = (const float*)d_in[0];
  // d_in[1] = num_obj, d_in[2] = num_relation: constants, unused by the math
  const int*   pairs  = (const int*)  d_in[3];
  const float* w1     = (const float*)d_in[4];
  const float* b1     = (const float*)d_in[5];
  const float* w2     = (const float*)d_in[6];
  const float* b2     = (const float*)d_in[7];
  const float* fcw    = (const float*)d_in[8];
  const float* fcb    = (const float*)d_in[9];
  float* out = (float*)d_out;

  const u64 xs_bytes = (u64)1024 * 115200;
  if (ws_size >= xs_bytes + 102400) {
    // fast path: prepack_g -> conv1 -> conv2 (80B-stride LDS conflict fix).
    // Gt (24576 B) lives in the FRONT of `out`: written by prepack_g, read
    // by conv1, then fully overwritten by conv2's out-write (stream order).
    unsigned short* XsG = (unsigned short*)d_ws;
    unsigned short* Wr  = (unsigned short*)((char*)d_ws + xs_bytes);
    unsigned short* Gt  = (unsigned short*)d_out;
    prepack_g<<<24, 512, 0, stream>>>(w1, Gt);
    conv1_kernel<<<1049, 512, 24576, stream>>>(bboxes, pairs, Gt, b1, w2, XsG, Wr);
    conv2_kernel<<<1024, 512, 74688, stream>>>(XsG, Wr, b2, fcw, fcb, out);
  } else {
    // fallback: round-7 fused path
    unsigned short* Wr = (unsigned short*)d_ws;                      // 102400 B
    unsigned short* Gt = (unsigned short*)((char*)d_ws + 102400);    //  24576 B
    prepack<<<248, 256, 0, stream>>>(w1, w2, Wr, Gt);
    fused_kernel<<<1024, 512, 147936, stream>>>(bboxes, pairs, Gt, b1, Wr, b2,
                                                fcw, fcb, out);
  }
}